// Round 1
// baseline (791.201 us; speedup 1.0000x reference)
//
#include <hip/hip_runtime.h>

// ---------------------------------------------------------------------------
// RNNAgent forward: fc1+ReLU -> GRUCell -> two Q heads (interleaved), bf16 MFMA
// B=65536, IN2=256, H2=512, A=32.  All inputs fp32; compute in bf16 MFMA with
// fp32 accumulate; GRU gate math in fp32.
// ---------------------------------------------------------------------------

#define BATCH 65536
#define IN2   256
#define H2    512
#define NA    32
#define QELEMS (2 * BATCH * NA)   // 4194304 floats (q section of d_out)

typedef float  f32x4  __attribute__((ext_vector_type(4)));
typedef short  short8 __attribute__((ext_vector_type(8)));
typedef __bf16 bf16x8 __attribute__((ext_vector_type(8)));

__device__ __forceinline__ f32x4 mfma16(short8 a, short8 b, f32x4 c) {
  return __builtin_amdgcn_mfma_f32_16x16x32_bf16(
      __builtin_bit_cast(bf16x8, a), __builtin_bit_cast(bf16x8, b), c, 0, 0, 0);
}

__device__ __forceinline__ unsigned short f2bf(float f) {
  union { float f; unsigned u; } v; v.f = f;
  unsigned r = v.u + 0x7fffu + ((v.u >> 16) & 1u);
  return (unsigned short)(r >> 16);
}

// ---------------------------------------------------------------------------
// fp32 -> bf16 convert (vectorized, grid-stride)
// ---------------------------------------------------------------------------
__global__ void cvt_kernel(const float* __restrict__ s,
                           unsigned short* __restrict__ d, int n4) {
  for (int i = blockIdx.x * blockDim.x + threadIdx.x; i < n4;
       i += gridDim.x * blockDim.x) {
    float4 f = ((const float4*)s)[i];
    ushort4 o;
    o.x = f2bf(f.x); o.y = f2bf(f.y); o.z = f2bf(f.z); o.w = f2bf(f.w);
    ((ushort4*)d)[i] = o;
  }
}

// ---------------------------------------------------------------------------
// fc1: x = relu(in @ W1^T + b1); in16 [B][256], W1 [512][256] -> x16 [B][512]
// Block tile 128x64, 4 waves as 2x2 (wave = 64 rows x 32 cols), BK=64.
// ---------------------------------------------------------------------------
__global__ __launch_bounds__(256, 2)
void fc1_kernel(const unsigned short* __restrict__ A,
                const unsigned short* __restrict__ W,
                const float* __restrict__ bias,
                unsigned short* __restrict__ X) {
  __shared__ unsigned short As[128][72];
  __shared__ unsigned short Bs[64][72];
  const int tid  = threadIdx.x;
  const int lane = tid & 63, wid = tid >> 6;
  const int l16 = lane & 15, kg = (lane >> 4) * 8, rbase = (lane >> 4) * 4;
  const int row0 = blockIdx.x * 128;
  const int col0 = blockIdx.y * 64;
  const int wrow = (wid >> 1) * 64;
  const int wcol = (wid & 1) * 32;

  f32x4 acc[4][2] = {};

  for (int k0 = 0; k0 < IN2; k0 += 64) {
#pragma unroll
    for (int c = 0; c < 4; ++c) {          // A tile: 1024 chunks of 8 bf16
      int idx = tid + c * 256;
      int r = idx >> 3, k8 = idx & 7;
      uint4 v = *(const uint4*)&A[(row0 + r) * IN2 + k0 + k8 * 8];
      *(uint4*)&As[r][k8 * 8] = v;
    }
#pragma unroll
    for (int c = 0; c < 2; ++c) {          // B tile: 512 chunks
      int idx = tid + c * 256;
      int r = idx >> 3, k8 = idx & 7;
      uint4 v = *(const uint4*)&W[(col0 + r) * IN2 + k0 + k8 * 8];
      *(uint4*)&Bs[r][k8 * 8] = v;
    }
    __syncthreads();
#pragma unroll
    for (int kk = 0; kk < 64; kk += 32) {
      short8 af[4], bf[2];
#pragma unroll
      for (int m = 0; m < 4; ++m)
        af[m] = *(const short8*)&As[wrow + m * 16 + l16][kk + kg];
#pragma unroll
      for (int n = 0; n < 2; ++n)
        bf[n] = *(const short8*)&Bs[wcol + n * 16 + l16][kk + kg];
#pragma unroll
      for (int m = 0; m < 4; ++m)
#pragma unroll
        for (int n = 0; n < 2; ++n)
          acc[m][n] = mfma16(af[m], bf[n], acc[m][n]);
    }
    __syncthreads();
  }

#pragma unroll
  for (int m = 0; m < 4; ++m)
#pragma unroll
    for (int n = 0; n < 2; ++n) {
      int col = col0 + wcol + n * 16 + l16;
      float bv = bias[col];
#pragma unroll
      for (int e = 0; e < 4; ++e) {
        int row = row0 + wrow + m * 16 + rbase + e;
        float v = acc[m][n][e] + bv;
        v = v > 0.f ? v : 0.f;
        X[row * H2 + col] = f2bf(v);
      }
    }
}

// ---------------------------------------------------------------------------
// GRU: for a 128x32 tile of (batch, j): compute 6 GEMM slabs
//   gi_r/z/n = x @ W_ih[g*512+j]^T   gh_r/z/n = h @ W_hh[g*512+j]^T
// then full GRUCell gate math; writes h (fp32) to out_h.
// 4 waves, each 32 rows x 32 cols. BK=64, K=512.
// ---------------------------------------------------------------------------
__global__ __launch_bounds__(256, 2)
void gru_kernel(const unsigned short* __restrict__ X16,
                const unsigned short* __restrict__ H16,
                const unsigned short* __restrict__ Wih,
                const unsigned short* __restrict__ Whh,
                const float* __restrict__ b_ih,
                const float* __restrict__ b_hh,
                const float* __restrict__ hidden,
                float* __restrict__ out_h) {
  __shared__ unsigned short Xs[128][72];
  __shared__ unsigned short Hs[128][72];
  __shared__ unsigned short Ws[6][32][72];

  const int tid  = threadIdx.x;
  const int lane = tid & 63, wid = tid >> 6;
  const int l16 = lane & 15, kg = (lane >> 4) * 8, rbase = (lane >> 4) * 4;
  const int row0 = blockIdx.x * 128;
  const int j0   = blockIdx.y * 32;
  const int wrow = wid * 32;

  f32x4 accI[3][2][2] = {};
  f32x4 accH[3][2][2] = {};

  for (int k0 = 0; k0 < H2; k0 += 64) {
#pragma unroll
    for (int c = 0; c < 4; ++c) {          // Xs: 1024 chunks
      int idx = tid + c * 256;
      int r = idx >> 3, k8 = idx & 7;
      *(uint4*)&Xs[r][k8 * 8] =
          *(const uint4*)&X16[(row0 + r) * H2 + k0 + k8 * 8];
    }
#pragma unroll
    for (int c = 0; c < 4; ++c) {          // Hs: 1024 chunks
      int idx = tid + c * 256;
      int r = idx >> 3, k8 = idx & 7;
      *(uint4*)&Hs[r][k8 * 8] =
          *(const uint4*)&H16[(row0 + r) * H2 + k0 + k8 * 8];
    }
#pragma unroll
    for (int c = 0; c < 6; ++c) {          // Ws: 6 slabs x 256 chunks
      int idx = tid + c * 256;
      int slab = idx >> 8, rem = idx & 255;
      int r = rem >> 3, k8 = rem & 7;
      const unsigned short* src =
          (slab < 3) ? &Wih[(slab * H2 + j0 + r) * H2]
                     : &Whh[((slab - 3) * H2 + j0 + r) * H2];
      *(uint4*)&Ws[slab][r][k8 * 8] = *(const uint4*)&src[k0 + k8 * 8];
    }
    __syncthreads();
#pragma unroll
    for (int kk = 0; kk < 64; kk += 32) {
      short8 ax[2], ah[2], bw[6][2];
#pragma unroll
      for (int m = 0; m < 2; ++m) {
        ax[m] = *(const short8*)&Xs[wrow + m * 16 + l16][kk + kg];
        ah[m] = *(const short8*)&Hs[wrow + m * 16 + l16][kk + kg];
      }
#pragma unroll
      for (int g = 0; g < 6; ++g)
#pragma unroll
        for (int n = 0; n < 2; ++n)
          bw[g][n] = *(const short8*)&Ws[g][n * 16 + l16][kk + kg];
#pragma unroll
      for (int g = 0; g < 3; ++g)
#pragma unroll
        for (int m = 0; m < 2; ++m)
#pragma unroll
          for (int n = 0; n < 2; ++n) {
            accI[g][m][n] = mfma16(ax[m], bw[g][n], accI[g][m][n]);
            accH[g][m][n] = mfma16(ah[m], bw[3 + g][n], accH[g][m][n]);
          }
    }
    __syncthreads();
  }

#pragma unroll
  for (int m = 0; m < 2; ++m)
#pragma unroll
    for (int n = 0; n < 2; ++n) {
      int j = j0 + n * 16 + l16;
      float bir = b_ih[j],        bhr = b_hh[j];
      float biz = b_ih[H2 + j],   bhz = b_hh[H2 + j];
      float bin = b_ih[2*H2 + j], bhn = b_hh[2*H2 + j];
#pragma unroll
      for (int e = 0; e < 4; ++e) {
        int row = row0 + wrow + m * 16 + rbase + e;
        float ir = accI[0][m][n][e] + bir;
        float iz = accI[1][m][n][e] + biz;
        float in_ = accI[2][m][n][e] + bin;
        float hr = accH[0][m][n][e] + bhr;
        float hz = accH[1][m][n][e] + bhz;
        float hn = accH[2][m][n][e] + bhn;
        float r = 1.f / (1.f + __expf(-(ir + hr)));
        float z = 1.f / (1.f + __expf(-(iz + hz)));
        float nn = tanhf(in_ + r * hn);
        float hp = hidden[row * H2 + j];
        out_h[row * H2 + j] = (1.f - z) * nn + z * hp;
      }
    }
}

// ---------------------------------------------------------------------------
// heads: q1 = h @ W21^T + b21, q2 = h @ W22^T + b22, interleaved rows.
// h is read as fp32 from d_out's h-section and converted during staging.
// Block = 64 rows; 4 waves x 16 rows; each wave does both heads (32 cols).
// ---------------------------------------------------------------------------
__global__ __launch_bounds__(256, 2)
void heads_kernel(const float* __restrict__ Hsrc,
                  const unsigned short* __restrict__ Wq1,
                  const unsigned short* __restrict__ Wq2,
                  const float* __restrict__ b21,
                  const float* __restrict__ b22,
                  float* __restrict__ outq) {
  __shared__ unsigned short Hs[64][72];
  __shared__ unsigned short Wq[2][32][72];
  const int tid  = threadIdx.x;
  const int lane = tid & 63, wid = tid >> 6;
  const int l16 = lane & 15, kg = (lane >> 4) * 8, rbase = (lane >> 4) * 4;
  const int row0 = blockIdx.x * 64;
  const int wrow = wid * 16;

  f32x4 acc[2][2] = {};

  for (int k0 = 0; k0 < H2; k0 += 64) {
#pragma unroll
    for (int c = 0; c < 4; ++c) {          // Hs: 1024 float4 chunks (cvt)
      int idx = tid + c * 256;
      int r = idx >> 4, c4 = idx & 15;
      float4 f = *(const float4*)&Hsrc[(row0 + r) * H2 + k0 + c4 * 4];
      ushort4 o;
      o.x = f2bf(f.x); o.y = f2bf(f.y); o.z = f2bf(f.z); o.w = f2bf(f.w);
      *(ushort4*)&Hs[r][c4 * 4] = o;
    }
#pragma unroll
    for (int c = 0; c < 2; ++c) {          // Wq: 2 slabs x 256 chunks
      int idx = tid + c * 256;
      int slab = idx >> 8, rem = idx & 255;
      int r = rem >> 3, k8 = rem & 7;
      const unsigned short* src = slab ? Wq2 : Wq1;
      *(uint4*)&Wq[slab][r][k8 * 8] = *(const uint4*)&src[r * H2 + k0 + k8 * 8];
    }
    __syncthreads();
#pragma unroll
    for (int kk = 0; kk < 64; kk += 32) {
      short8 a = *(const short8*)&Hs[wrow + l16][kk + kg];
#pragma unroll
      for (int hd = 0; hd < 2; ++hd)
#pragma unroll
        for (int n = 0; n < 2; ++n) {
          short8 b = *(const short8*)&Wq[hd][n * 16 + l16][kk + kg];
          acc[hd][n] = mfma16(a, b, acc[hd][n]);
        }
    }
    __syncthreads();
  }

#pragma unroll
  for (int hd = 0; hd < 2; ++hd)
#pragma unroll
    for (int n = 0; n < 2; ++n) {
      int col = n * 16 + l16;
      float bv = hd ? b22[col] : b21[col];
#pragma unroll
      for (int e = 0; e < 4; ++e) {
        int row = row0 + wrow + rbase + e;
        outq[(2 * row + hd) * NA + col] = acc[hd][n][e] + bv;
      }
    }
}

// ---------------------------------------------------------------------------
extern "C" void kernel_launch(void* const* d_in, const int* in_sizes, int n_in,
                              void* d_out, int out_size, void* d_ws,
                              size_t ws_size, hipStream_t stream) {
  (void)in_sizes; (void)n_in; (void)out_size; (void)ws_size;
  const float* inputs = (const float*)d_in[0];
  const float* hidden = (const float*)d_in[1];
  const float* W1     = (const float*)d_in[2];
  const float* b1     = (const float*)d_in[3];
  const float* W_ih   = (const float*)d_in[4];
  const float* W_hh   = (const float*)d_in[5];
  const float* b_ih   = (const float*)d_in[6];
  const float* b_hh   = (const float*)d_in[7];
  const float* W21    = (const float*)d_in[8];
  const float* b21    = (const float*)d_in[9];
  const float* W22    = (const float*)d_in[10];
  const float* b22    = (const float*)d_in[11];
  float* out = (float*)d_out;

  char* ws = (char*)d_ws;
  size_t off = 0;
  unsigned short* in16  = (unsigned short*)(ws + off); off += (size_t)BATCH * IN2 * 2;
  unsigned short* h16   = (unsigned short*)(ws + off); off += (size_t)BATCH * H2 * 2;
  unsigned short* x16   = (unsigned short*)(ws + off); off += (size_t)BATCH * H2 * 2;
  unsigned short* W1_16 = (unsigned short*)(ws + off); off += (size_t)H2 * IN2 * 2;
  unsigned short* Wih16 = (unsigned short*)(ws + off); off += (size_t)3 * H2 * H2 * 2;
  unsigned short* Whh16 = (unsigned short*)(ws + off); off += (size_t)3 * H2 * H2 * 2;
  unsigned short* W2116 = (unsigned short*)(ws + off); off += (size_t)NA * H2 * 2;
  unsigned short* W2216 = (unsigned short*)(ws + off); off += (size_t)NA * H2 * 2;

  auto cvt = [&](const float* s, unsigned short* d, int n) {
    int n4 = n / 4;
    int blocks = (n4 + 255) / 256;
    if (blocks > 8192) blocks = 8192;
    cvt_kernel<<<blocks, 256, 0, stream>>>(s, d, n4);
  };
  cvt(inputs, in16, BATCH * IN2);
  cvt(hidden, h16, BATCH * H2);
  cvt(W1, W1_16, H2 * IN2);
  cvt(W_ih, Wih16, 3 * H2 * H2);
  cvt(W_hh, Whh16, 3 * H2 * H2);
  cvt(W21, W2116, NA * H2);
  cvt(W22, W2216, NA * H2);

  fc1_kernel<<<dim3(BATCH / 128, H2 / 64), 256, 0, stream>>>(in16, W1_16, b1, x16);

  float* out_h = out + QELEMS;
  gru_kernel<<<dim3(BATCH / 128, H2 / 32), 256, 0, stream>>>(
      x16, h16, Wih16, Whh16, b_ih, b_hh, hidden, out_h);

  heads_kernel<<<BATCH / 64, 256, 0, stream>>>(out_h, W2116, W2216, b21, b22, out);
}

// Round 2
// 644.244 us; speedup vs baseline: 1.2281x; 1.2281x over previous
//
#include <hip/hip_runtime.h>

// ---------------------------------------------------------------------------
// RNNAgent forward: fc1+ReLU -> GRUCell -> two Q heads (interleaved), bf16 MFMA
// B=65536, IN2=256, H2=512, A=32.
// v2: global_load_lds staging + XOR-swizzled LDS, 128x64 GRU tile, merged r/z
// accumulators, bf16 hidden in epilogue, fused weight cvt, fewer launches.
// ---------------------------------------------------------------------------

#define BATCH 65536
#define IN2   256
#define H2    512
#define NA    32
#define QELEMS (2 * BATCH * NA)

typedef float  f32x4  __attribute__((ext_vector_type(4)));
typedef short  short8 __attribute__((ext_vector_type(8)));
typedef __bf16 bf16x8 __attribute__((ext_vector_type(8)));

__device__ __forceinline__ f32x4 mfma16(short8 a, short8 b, f32x4 c) {
  return __builtin_amdgcn_mfma_f32_16x16x32_bf16(
      __builtin_bit_cast(bf16x8, a), __builtin_bit_cast(bf16x8, b), c, 0, 0, 0);
}

__device__ __forceinline__ unsigned short f2bf(float f) {
  union { float f; unsigned u; } v; v.f = f;
  unsigned r = v.u + 0x7fffu + ((v.u >> 16) & 1u);
  return (unsigned short)(r >> 16);
}
__device__ __forceinline__ float bf2f(unsigned short u) {
  union { unsigned u; float f; } v; v.u = ((unsigned)u) << 16; return v.f;
}

__device__ __forceinline__ void gload16(const void* g, void* l) {
  __builtin_amdgcn_global_load_lds(
      (const __attribute__((address_space(1))) void*)g,
      (__attribute__((address_space(3))) void*)l, 16, 0, 0);
}

__device__ __forceinline__ float sigm(float x) {
  return 1.f / (1.f + __expf(-x));
}
__device__ __forceinline__ float tanh_fast(float x) {
  float t = __expf(-2.f * fabsf(x));          // in (0,1], no overflow
  float r = (1.f - t) / (1.f + t);
  return x >= 0.f ? r : -r;
}

// ---------------------------------------------------------------------------
// fp32 -> bf16 convert (generic, grid-stride over float4)
// ---------------------------------------------------------------------------
__global__ void cvt_kernel(const float* __restrict__ s,
                           unsigned short* __restrict__ d, int n4) {
  for (int i = blockIdx.x * blockDim.x + threadIdx.x; i < n4;
       i += gridDim.x * blockDim.x) {
    float4 f = ((const float4*)s)[i];
    ushort4 o;
    o.x = f2bf(f.x); o.y = f2bf(f.y); o.z = f2bf(f.z); o.w = f2bf(f.w);
    ((ushort4*)d)[i] = o;
  }
}

// ---------------------------------------------------------------------------
// fused weight cvt: W1, Wih, Whh, W21, W22 in one launch.
// f4-unit segment sizes: 32768, 196608, 196608, 4096, 4096 (total 434176)
// ---------------------------------------------------------------------------
__global__ void cvtw_kernel(const float* __restrict__ W1,
                            const float* __restrict__ Wih,
                            const float* __restrict__ Whh,
                            const float* __restrict__ W21,
                            const float* __restrict__ W22,
                            unsigned short* __restrict__ dW1,
                            unsigned short* __restrict__ dWih,
                            unsigned short* __restrict__ dWhh,
                            unsigned short* __restrict__ dW21,
                            unsigned short* __restrict__ dW22) {
  int i = blockIdx.x * blockDim.x + threadIdx.x;
  const float* s; unsigned short* d; int local;
  if      (i < 32768)  { s = W1;  d = dW1;  local = i; }
  else if (i < 229376) { s = Wih; d = dWih; local = i - 32768; }
  else if (i < 425984) { s = Whh; d = dWhh; local = i - 229376; }
  else if (i < 430080) { s = W21; d = dW21; local = i - 425984; }
  else if (i < 434176) { s = W22; d = dW22; local = i - 430080; }
  else return;
  float4 f = ((const float4*)s)[local];
  ushort4 o;
  o.x = f2bf(f.x); o.y = f2bf(f.y); o.z = f2bf(f.z); o.w = f2bf(f.w);
  ((ushort4*)d)[local] = o;
}

// ---------------------------------------------------------------------------
// fc1: x = relu(in @ W1^T + b1); in fp32 [B][256] (cvt during staging),
// W1_16 bf16 [512][256] -> x16 [B][512].  128x64 tile, 4 waves 2x2.
// ---------------------------------------------------------------------------
__global__ __launch_bounds__(256, 2)
void fc1_kernel(const float* __restrict__ A,
                const unsigned short* __restrict__ W,
                const float* __restrict__ bias,
                unsigned short* __restrict__ X) {
  __shared__ unsigned short As[128][72];
  __shared__ unsigned short Bs[64][72];
  const int tid  = threadIdx.x;
  const int lane = tid & 63, wid = tid >> 6;
  const int l16 = lane & 15, kg = (lane >> 4) * 8, rbase = (lane >> 4) * 4;
  const int row0 = blockIdx.x * 128;
  const int col0 = blockIdx.y * 64;
  const int wrow = (wid >> 1) * 64;
  const int wcol = (wid & 1) * 32;

  f32x4 acc[4][2] = {};

  for (int k0 = 0; k0 < IN2; k0 += 64) {
#pragma unroll
    for (int c = 0; c < 4; ++c) {          // A: fp32 -> bf16 staging
      int idx = tid + c * 256;
      int r = idx >> 3, k8 = idx & 7;
      const float* src = &A[(size_t)(row0 + r) * IN2 + k0 + k8 * 8];
      float4 f0 = *(const float4*)src;
      float4 f1 = *(const float4*)(src + 4);
      uint4 o;
      o.x = f2bf(f0.x) | ((unsigned)f2bf(f0.y) << 16);
      o.y = f2bf(f0.z) | ((unsigned)f2bf(f0.w) << 16);
      o.z = f2bf(f1.x) | ((unsigned)f2bf(f1.y) << 16);
      o.w = f2bf(f1.z) | ((unsigned)f2bf(f1.w) << 16);
      *(uint4*)&As[r][k8 * 8] = o;
    }
#pragma unroll
    for (int c = 0; c < 2; ++c) {          // W tile (already bf16)
      int idx = tid + c * 256;
      int r = idx >> 3, k8 = idx & 7;
      *(uint4*)&Bs[r][k8 * 8] =
          *(const uint4*)&W[(size_t)(col0 + r) * IN2 + k0 + k8 * 8];
    }
    __syncthreads();
#pragma unroll
    for (int kk = 0; kk < 64; kk += 32) {
      short8 af[4], bf[2];
#pragma unroll
      for (int m = 0; m < 4; ++m)
        af[m] = *(const short8*)&As[wrow + m * 16 + l16][kk + kg];
#pragma unroll
      for (int n = 0; n < 2; ++n)
        bf[n] = *(const short8*)&Bs[wcol + n * 16 + l16][kk + kg];
#pragma unroll
      for (int m = 0; m < 4; ++m)
#pragma unroll
        for (int n = 0; n < 2; ++n)
          acc[m][n] = mfma16(af[m], bf[n], acc[m][n]);
    }
    __syncthreads();
  }

#pragma unroll
  for (int m = 0; m < 4; ++m)
#pragma unroll
    for (int n = 0; n < 2; ++n) {
      int col = col0 + wcol + n * 16 + l16;
      float bv = bias[col];
#pragma unroll
      for (int e = 0; e < 4; ++e) {
        int row = row0 + wrow + m * 16 + rbase + e;
        float v = acc[m][n][e] + bv;
        v = v > 0.f ? v : 0.f;
        X[(size_t)row * H2 + col] = f2bf(v);
      }
    }
}

// ---------------------------------------------------------------------------
// GRU: tile 128 rows x 64 j, 4 waves (2x2: each 64r x 32j), 6 weight panels.
// Merged r/z accumulators (i_r+h_r, i_z+h_z).  global_load_lds staging with
// XOR-swizzled source, linear LDS, swizzled ds_read.  LDS = 80 KB.
// ---------------------------------------------------------------------------
__global__ __launch_bounds__(256, 2)
void gru_kernel(const unsigned short* __restrict__ X16,
                const unsigned short* __restrict__ H16,
                const unsigned short* __restrict__ Wih,
                const unsigned short* __restrict__ Whh,
                const float* __restrict__ b_ih,
                const float* __restrict__ b_hh,
                float* __restrict__ out_h,
                unsigned short* __restrict__ h16b) {
  // layout (bytes): Xs [0,16384)  Hs [16384,32768)  Ws [32768 + s*8192)
  __shared__ unsigned short lds[40960];   // 80 KB
  char* ldsb = (char*)lds;

  const int tid  = threadIdx.x;
  const int lane = tid & 63, wid = tid >> 6;
  const int l16 = lane & 15;
  const int row0 = blockIdx.x * 128;
  const int j0   = blockIdx.y * 64;
  const int wrow = (wid >> 1) * 64;
  const int wcol = (wid & 1) * 32;

  // staging lane constants: chunk r = ..+ (lane>>3), p = lane&7
  const int lr   = lane >> 3;
  const int scol = ((lane & 7) ^ (lr & 7)) * 8;   // pre-swizzled source col
  const unsigned short* gx = X16 + (size_t)(row0 + wid * 32 + lr) * H2 + scol;
  const unsigned short* gh = H16 + (size_t)(row0 + wid * 32 + lr) * H2 + scol;

  f32x4 accR[4][2] = {}, accZ[4][2] = {}, accIN[4][2] = {}, accHN[4][2] = {};

  for (int k0 = 0; k0 < H2; k0 += 64) {
#pragma unroll
    for (int i = 0; i < 4; ++i) {         // X, H: 4 issues each per wave
      gload16(gx + k0 + i * 8 * H2, ldsb + (wid * 4 + i) * 1024);
      gload16(gh + k0 + i * 8 * H2, ldsb + 16384 + (wid * 4 + i) * 1024);
    }
#pragma unroll
    for (int i = 0; i < 12; ++i) {        // 6 W panels: 12 issues per wave
      int g = wid * 12 + i;               // 0..47 chunk-groups
      int s = g >> 3;                     // panel 0..5
      int r = (g & 7) * 8 + lr;           // row within panel (j0-relative)
      const unsigned short* src =
          (s < 3) ? Wih + (size_t)(s * H2 + j0 + r) * H2
                  : Whh + (size_t)((s - 3) * H2 + j0 + r) * H2;
      gload16(src + k0 + scol, ldsb + 32768 + g * 1024);
    }
    __syncthreads();

#pragma unroll
    for (int kk = 0; kk < 64; kk += 32) {
      const int cch = (kk >> 3) + (lane >> 4);    // logical 16B-chunk col
      short8 ax[4], ah[4];
#pragma unroll
      for (int m = 0; m < 4; ++m) {
        int r = wrow + m * 16 + l16;
        int off = r * 128 + ((cch ^ (r & 7)) << 4);
        ax[m] = *(const short8*)(ldsb + off);
        ah[m] = *(const short8*)(ldsb + 16384 + off);
      }
#pragma unroll
      for (int n = 0; n < 2; ++n) {
        int rr = wcol + n * 16 + l16;
        int woff = 32768 + rr * 128 + ((cch ^ (rr & 7)) << 4);
        short8 b0 = *(const short8*)(ldsb + woff);              // ih_r
        short8 b3 = *(const short8*)(ldsb + woff + 3 * 8192);   // hh_r
#pragma unroll
        for (int m = 0; m < 4; ++m) {
          accR[m][n] = mfma16(ax[m], b0, accR[m][n]);
          accR[m][n] = mfma16(ah[m], b3, accR[m][n]);
        }
        short8 b1 = *(const short8*)(ldsb + woff + 1 * 8192);   // ih_z
        short8 b4 = *(const short8*)(ldsb + woff + 4 * 8192);   // hh_z
#pragma unroll
        for (int m = 0; m < 4; ++m) {
          accZ[m][n] = mfma16(ax[m], b1, accZ[m][n]);
          accZ[m][n] = mfma16(ah[m], b4, accZ[m][n]);
        }
        short8 b2 = *(const short8*)(ldsb + woff + 2 * 8192);   // ih_n
        short8 b5 = *(const short8*)(ldsb + woff + 5 * 8192);   // hh_n
#pragma unroll
        for (int m = 0; m < 4; ++m) {
          accIN[m][n] = mfma16(ax[m], b2, accIN[m][n]);
          accHN[m][n] = mfma16(ah[m], b5, accHN[m][n]);
        }
      }
    }
    __syncthreads();
  }

  const int rbase = (lane >> 4) * 4;
#pragma unroll
  for (int n = 0; n < 2; ++n) {
    int j = j0 + wcol + n * 16 + l16;
    float brr = b_ih[j] + b_hh[j];
    float bzz = b_ih[H2 + j] + b_hh[H2 + j];
    float bin = b_ih[2 * H2 + j];
    float bhn = b_hh[2 * H2 + j];
#pragma unroll
    for (int m = 0; m < 4; ++m) {
#pragma unroll
      for (int e = 0; e < 4; ++e) {
        int row = row0 + wrow + m * 16 + rbase + e;
        float r  = sigm(accR[m][n][e] + brr);
        float z  = sigm(accZ[m][n][e] + bzz);
        float nn = tanh_fast(accIN[m][n][e] + bin + r * (accHN[m][n][e] + bhn));
        float hp = bf2f(H16[(size_t)row * H2 + j]);
        float h  = (1.f - z) * nn + z * hp;
        out_h[(size_t)row * H2 + j] = h;
        if (h16b) h16b[(size_t)row * H2 + j] = f2bf(h);
      }
    }
  }
}

// ---------------------------------------------------------------------------
// heads from bf16 h: q1/q2 interleaved.  64-row blocks, 4 waves x 16 rows.
// ---------------------------------------------------------------------------
__global__ __launch_bounds__(256, 2)
void heads_bf16_kernel(const unsigned short* __restrict__ Hsrc,
                       const unsigned short* __restrict__ Wq1,
                       const unsigned short* __restrict__ Wq2,
                       const float* __restrict__ b21,
                       const float* __restrict__ b22,
                       float* __restrict__ outq) {
  __shared__ unsigned short Hs[64][72];
  __shared__ unsigned short Wq[2][32][72];
  const int tid  = threadIdx.x;
  const int lane = tid & 63, wid = tid >> 6;
  const int l16 = lane & 15, kg = (lane >> 4) * 8, rbase = (lane >> 4) * 4;
  const int row0 = blockIdx.x * 64;
  const int wrow = wid * 16;

  f32x4 acc[2][2] = {};

  for (int k0 = 0; k0 < H2; k0 += 64) {
#pragma unroll
    for (int c = 0; c < 2; ++c) {
      int idx = tid + c * 256;
      int r = idx >> 3, k8 = idx & 7;
      *(uint4*)&Hs[r][k8 * 8] =
          *(const uint4*)&Hsrc[(size_t)(row0 + r) * H2 + k0 + k8 * 8];
    }
#pragma unroll
    for (int c = 0; c < 2; ++c) {
      int idx = tid + c * 256;
      int slab = idx >> 8, rem = idx & 255;
      int r = rem >> 3, k8 = rem & 7;
      const unsigned short* src = slab ? Wq2 : Wq1;
      *(uint4*)&Wq[slab][r][k8 * 8] =
          *(const uint4*)&src[(size_t)r * H2 + k0 + k8 * 8];
    }
    __syncthreads();
#pragma unroll
    for (int kk = 0; kk < 64; kk += 32) {
      short8 a = *(const short8*)&Hs[wrow + l16][kk + kg];
#pragma unroll
      for (int hd = 0; hd < 2; ++hd)
#pragma unroll
        for (int n = 0; n < 2; ++n) {
          short8 b = *(const short8*)&Wq[hd][n * 16 + l16][kk + kg];
          acc[hd][n] = mfma16(a, b, acc[hd][n]);
        }
    }
    __syncthreads();
  }

#pragma unroll
  for (int hd = 0; hd < 2; ++hd)
#pragma unroll
    for (int n = 0; n < 2; ++n) {
      int col = n * 16 + l16;
      float bv = hd ? b22[col] : b21[col];
#pragma unroll
      for (int e = 0; e < 4; ++e) {
        int row = row0 + wrow + rbase + e;
        outq[(size_t)(2 * row + hd) * NA + col] = acc[hd][n][e] + bv;
      }
    }
}

// fallback: heads reading fp32 h (cvt during staging)
__global__ __launch_bounds__(256, 2)
void heads_f32_kernel(const float* __restrict__ Hsrc,
                      const unsigned short* __restrict__ Wq1,
                      const unsigned short* __restrict__ Wq2,
                      const float* __restrict__ b21,
                      const float* __restrict__ b22,
                      float* __restrict__ outq) {
  __shared__ unsigned short Hs[64][72];
  __shared__ unsigned short Wq[2][32][72];
  const int tid  = threadIdx.x;
  const int lane = tid & 63, wid = tid >> 6;
  const int l16 = lane & 15, kg = (lane >> 4) * 8, rbase = (lane >> 4) * 4;
  const int row0 = blockIdx.x * 64;
  const int wrow = wid * 16;

  f32x4 acc[2][2] = {};

  for (int k0 = 0; k0 < H2; k0 += 64) {
#pragma unroll
    for (int c = 0; c < 4; ++c) {
      int idx = tid + c * 256;
      int r = idx >> 4, c4 = idx & 15;
      float4 f = *(const float4*)&Hsrc[(size_t)(row0 + r) * H2 + k0 + c4 * 4];
      ushort4 o;
      o.x = f2bf(f.x); o.y = f2bf(f.y); o.z = f2bf(f.z); o.w = f2bf(f.w);
      *(ushort4*)&Hs[r][c4 * 4] = o;
    }
#pragma unroll
    for (int c = 0; c < 2; ++c) {
      int idx = tid + c * 256;
      int slab = idx >> 8, rem = idx & 255;
      int r = rem >> 3, k8 = rem & 7;
      const unsigned short* src = slab ? Wq2 : Wq1;
      *(uint4*)&Wq[slab][r][k8 * 8] =
          *(const uint4*)&src[(size_t)r * H2 + k0 + k8 * 8];
    }
    __syncthreads();
#pragma unroll
    for (int kk = 0; kk < 64; kk += 32) {
      short8 a = *(const short8*)&Hs[wrow + l16][kk + kg];
#pragma unroll
      for (int hd = 0; hd < 2; ++hd)
#pragma unroll
        for (int n = 0; n < 2; ++n) {
          short8 b = *(const short8*)&Wq[hd][n * 16 + l16][kk + kg];
          acc[hd][n] = mfma16(a, b, acc[hd][n]);
        }
    }
    __syncthreads();
  }

#pragma unroll
  for (int hd = 0; hd < 2; ++hd)
#pragma unroll
    for (int n = 0; n < 2; ++n) {
      int col = n * 16 + l16;
      float bv = hd ? b22[col] : b21[col];
#pragma unroll
      for (int e = 0; e < 4; ++e) {
        int row = row0 + wrow + rbase + e;
        outq[(size_t)(2 * row + hd) * NA + col] = acc[hd][n][e] + bv;
      }
    }
}

// ---------------------------------------------------------------------------
extern "C" void kernel_launch(void* const* d_in, const int* in_sizes, int n_in,
                              void* d_out, int out_size, void* d_ws,
                              size_t ws_size, hipStream_t stream) {
  (void)in_sizes; (void)n_in; (void)out_size;
  const float* inputs = (const float*)d_in[0];
  const float* hidden = (const float*)d_in[1];
  const float* W1     = (const float*)d_in[2];
  const float* b1     = (const float*)d_in[3];
  const float* W_ih   = (const float*)d_in[4];
  const float* W_hh   = (const float*)d_in[5];
  const float* b_ih   = (const float*)d_in[6];
  const float* b_hh   = (const float*)d_in[7];
  const float* W21    = (const float*)d_in[8];
  const float* b21    = (const float*)d_in[9];
  const float* W22    = (const float*)d_in[10];
  const float* b22    = (const float*)d_in[11];
  float* out = (float*)d_out;

  char* ws = (char*)d_ws;
  size_t off = 0;
  unsigned short* h16   = (unsigned short*)(ws + off); off += (size_t)BATCH * H2 * 2;
  unsigned short* x16   = (unsigned short*)(ws + off); off += (size_t)BATCH * H2 * 2;
  unsigned short* W1_16 = (unsigned short*)(ws + off); off += (size_t)H2 * IN2 * 2;
  unsigned short* Wih16 = (unsigned short*)(ws + off); off += (size_t)3 * H2 * H2 * 2;
  unsigned short* Whh16 = (unsigned short*)(ws + off); off += (size_t)3 * H2 * H2 * 2;
  unsigned short* W2116 = (unsigned short*)(ws + off); off += (size_t)NA * H2 * 2;
  unsigned short* W2216 = (unsigned short*)(ws + off); off += (size_t)NA * H2 * 2;
  size_t base_need = off;
  unsigned short* h16b = nullptr;
  if (ws_size >= base_need + (size_t)BATCH * H2 * 2)
    h16b = (unsigned short*)(ws + base_need);

  // hidden -> bf16
  cvt_kernel<<<8192, 256, 0, stream>>>(hidden, h16, BATCH * H2 / 4);
  // all weights -> bf16 (one launch)
  cvtw_kernel<<<1696, 256, 0, stream>>>(W1, W_ih, W_hh, W21, W22,
                                        W1_16, Wih16, Whh16, W2116, W2216);

  fc1_kernel<<<dim3(BATCH / 128, H2 / 64), 256, 0, stream>>>(inputs, W1_16, b1, x16);

  float* out_h = out + QELEMS;
  gru_kernel<<<dim3(BATCH / 128, H2 / 64), 256, 0, stream>>>(
      x16, h16, Wih16, Whh16, b_ih, b_hh, out_h, h16b);

  if (h16b)
    heads_bf16_kernel<<<BATCH / 64, 256, 0, stream>>>(h16b, W2116, W2216, b21, b22, out);
  else
    heads_f32_kernel<<<BATCH / 64, 256, 0, stream>>>(out_h, W2116, W2216, b21, b22, out);
}